// Round 5
// baseline (42.081 us; speedup 1.0000x reference)
//
#include <hip/hip_runtime.h>
#include <hip/hip_bf16.h>

typedef float f32x16 __attribute__((ext_vector_type(16)));
typedef float f32x4v __attribute__((ext_vector_type(4)));

#define GLOBAL_AS(p) ((const __attribute__((address_space(1))) void*)(p))
#define LDS_AS(p)    ((__attribute__((address_space(3))) void*)(p))

#define LP 8192
#define D 128
#define TWOEPS 2e-6f
#define CEPS 1.28e-10f   /* 128 * EPS^2 */
#define MARGIN 0.2f
#define NTRI 2080        /* 64*65/2 lower-triangular 128x128 tiles */

// ---------------- Phase A: normalize p rows -> fp8, compute w & q8 ----------------
// pb[row] = fp8_e4m3(p_hat)  (128 B / row)
// q8[row] = || fp8(p_hat) ||^2  (f32, of the ROUNDED vector -- removes fp8 norm bias)
// w[row]  = MARGIN - d_pn(row)  (d_pn in full f32, incl. eps terms)
__global__ __launch_bounds__(256) void rows_kernel(const float* __restrict__ p,
                                                   const float* __restrict__ n,
                                                   char* __restrict__ pb,
                                                   float* __restrict__ warr,
                                                   float* __restrict__ qarr) {
    int tid = threadIdx.x;
    int wave = tid >> 6, lane = tid & 63;
    int row = blockIdx.x * 4 + wave;
    // float2 per lane: 64 lanes x 2 floats = 128 = D
    float2 x = ((const float2*)(p + (size_t)row * D))[lane];
    float2 y = ((const float2*)n)[lane];  // n row 0 (t=0)
    float ssp = fmaf(x.x, x.x, x.y * x.y);
    float ssn = fmaf(y.x, y.x, y.y * y.y);
#pragma unroll
    for (int m = 1; m < 64; m <<= 1) {
        ssp += __shfl_xor(ssp, m);
        ssn += __shfl_xor(ssn, m);
    }
    float invp = 1.0f / fmaxf(sqrtf(ssp), 1e-12f);
    float invn = 1.0f / fmaxf(sqrtf(ssn), 1e-12f);
    float a0 = x.x * invp, a1 = x.y * invp;
    float h0 = y.x * invn, h1 = y.y * invn;

    // fp8 e4m3 (OCP) pack + decode for exact q8 of the rounded vector
    int pk = __builtin_amdgcn_cvt_pk_fp8_f32(a0, a1, 0, false);
    *(unsigned short*)(pb + (size_t)row * 128 + lane * 2) = (unsigned short)(pk & 0xffff);
    float b0 = __builtin_amdgcn_cvt_f32_fp8(pk, 0);
    float b1 = __builtin_amdgcn_cvt_f32_fp8(pk, 1);

    float q8 = fmaf(b0, b0, b1 * b1);
    float s  = a0 + a1;
    float q  = fmaf(a0, a0, a1 * a1);
    float dn = fmaf(a0, h0, a1 * h1);
    float sn = h0 + h1;
    float qn = fmaf(h0, h0, h1 * h1);
#pragma unroll
    for (int m = 1; m < 64; m <<= 1) {
        q8 += __shfl_xor(q8, m);
        s += __shfl_xor(s, m);
        q += __shfl_xor(q, m);
        dn += __shfl_xor(dn, m);
        sn += __shfl_xor(sn, m);
        qn += __shfl_xor(qn, m);
    }
    if (lane == 0) {
        float sq = q + qn - 2.0f * dn + TWOEPS * (s - sn) + CEPS;
        float dpn = sqrtf(fmaxf(sq, 0.0f));
        warr[row] = MARGIN - dpn;
        qarr[row] = q8;
    }
}

// ---------------- Phase B: triangular 128x128-tile pair kernel (fp8 MFMA) ----------------
// d(i,j) = sqrt(q8_i + q8_j - 2*dot8) is symmetric: off-diag tiles emit both
// ordered terms from one sqrt. 8 waves (2x4), each owns a 64x32 output via
// 32x32x16 fp8 MFMA (mt=2, ks=8).
// LDS panel layout per tile (16 KB): [kchunk 0..7][row 0..127][16 B]
//   -> fragment ds_read_b64 at stride 16 B across rows = conflict-free.
__global__ __launch_bounds__(512, 4) void pair_kernel(const char* __restrict__ pb,
                                                      const float* __restrict__ warr,
                                                      const float* __restrict__ qarr,
                                                      float* __restrict__ partials) {
    __shared__ __align__(16) char smem[32768];  // lA 16KB | lB 16KB
    char* lAc = smem;

    // triangular decode: b = ti*(ti+1)/2 + tj, tj <= ti
    const int b = blockIdx.x;
    int ti = (int)((__builtin_amdgcn_sqrtf(8.0f * (float)b + 1.0f) - 1.0f) * 0.5f);
    while ((ti + 1) * (ti + 2) / 2 <= b) ++ti;
    while (ti * (ti + 1) / 2 > b) --ti;
    const int tj = b - ti * (ti + 1) / 2;
    const bool diag = (ti == tj);

    char* lBc = diag ? lAc : (smem + 16384);

    const int tid = threadIdx.x;
    const int wave = tid >> 6, lane = tid & 63;
    const int i0 = ti * 128, j0 = tj * 128;

    const char* gA = pb + (size_t)i0 * 128;  // 128 B per fp8 row
    const char* gB = pb + (size_t)j0 * 128;

    // Stage: LDS offset o -> panel c = o>>11, row = (o>>4)&127, 16B chunk.
    // Global source byte = row*128 + c*16 (contiguous 16 B per lane ✓).
#pragma unroll
    for (int r = 0; r < 2; ++r) {
        int obase = wave * 2048 + r * 1024;  // wave-uniform LDS base
        int o = obase + lane * 16;
        int src = ((o >> 4) & 127) * 128 + ((o >> 11) << 4);
        __builtin_amdgcn_global_load_lds(GLOBAL_AS(gA + src), LDS_AS(lAc + obase), 16, 0, 0);
        if (!diag)
            __builtin_amdgcn_global_load_lds(GLOBAL_AS(gB + src), LDS_AS(lBc + obase), 16, 0, 0);
    }

    const int wr = wave >> 2, wc = wave & 3;  // 2x4 waves, each 64x32 output
    const int ln31 = lane & 31;
    const int h = lane >> 5;

    // Prefetch epilogue scalars (overlaps the stage; vmcnt drained by barrier).
    // i-rows per (mt, reg): i = i0 + wr*64 + mt*32 + (reg&3) + 8*(reg>>2) + 4*h
    //   -> per (mt, g=reg>>2): 4 consecutive rows at base + 8g + 4h  -> float4.
    const int ibase = i0 + wr * 64;
    f32x4v wiv[2][4], qiv[2][4];
#pragma unroll
    for (int mt = 0; mt < 2; ++mt)
#pragma unroll
        for (int g = 0; g < 4; ++g) {
            int ib = ibase + mt * 32 + 8 * g + 4 * h;
            wiv[mt][g] = *(const f32x4v*)(warr + ib);
            qiv[mt][g] = *(const f32x4v*)(qarr + ib);
        }
    const int j = j0 + wc * 32 + ln31;
    const float wj = warr[j];
    const float qj = qarr[j];

    __syncthreads();

    f32x16 acc[2] = {};

    // Fragments: A row = wr*64 + mt*32 + ln31, k-half h; B col = wc*32 + ln31.
#pragma unroll
    for (int ks = 0; ks < 8; ++ks) {
        const int koff = ks * 2048 + h * 8;
        long bvf = *(const long*)(lBc + koff + (wc * 32 + ln31) * 16);
#pragma unroll
        for (int mt = 0; mt < 2; ++mt) {
            long avf = *(const long*)(lAc + koff + (wr * 64 + mt * 32 + ln31) * 16);
            acc[mt] = __builtin_amdgcn_mfma_f32_32x32x16_fp8_fp8(avf, bvf, acc[mt], 0, 0, 0);
        }
    }

    // Epilogue. C/D 32x32 layout: col = lane&31, row = (reg&3)+8*(reg>>2)+4*h.
    float la = 0.0f, lb = 0.0f;
    if (diag) {
#pragma unroll
        for (int mt = 0; mt < 2; ++mt)
#pragma unroll
            for (int g = 0; g < 4; ++g)
#pragma unroll
                for (int r2 = 0; r2 < 4; ++r2) {
                    float dot = acc[mt][g * 4 + r2];
                    float sq = fmaf(-2.0f, dot, qiv[mt][g][r2] + qj);
                    float d = __builtin_amdgcn_sqrtf(fmaxf(sq, 0.0f));  // i==j can go <0
                    la += fmaxf(d + wiv[mt][g][r2], 0.0f);
                }
    } else {
        // off-diag pairs: true sq >= ~0.9 even with fp8 noise -> no clamp
#pragma unroll
        for (int mt = 0; mt < 2; ++mt)
#pragma unroll
            for (int g = 0; g < 4; ++g)
#pragma unroll
                for (int r2 = 0; r2 < 4; ++r2) {
                    float dot = acc[mt][g * 4 + r2];
                    float sq = fmaf(-2.0f, dot, qiv[mt][g][r2] + qj);
                    float d = __builtin_amdgcn_sqrtf(sq);
                    la += fmaxf(d + wiv[mt][g][r2], 0.0f);  // term (i,j)
                    lb += fmaxf(d + wj, 0.0f);              // term (j,i)
                }
    }
    float local = la + lb;

    // block reduction (deterministic)
#pragma unroll
    for (int m = 1; m < 64; m <<= 1) local += __shfl_xor(local, m);
    __syncthreads();  // all waves done with LDS tiles before reuse
    float* sred = (float*)smem;
    if (lane == 0) sred[wave] = local;
    __syncthreads();
    if (tid == 0) {
        float t0 = (sred[0] + sred[1]) + (sred[2] + sred[3]);
        float t1 = (sred[4] + sred[5]) + (sred[6] + sred[7]);
        partials[b] = t0 + t1;
    }
}

// ---------------- Phase C: final reduce ----------------
__global__ void reduce_kernel(const float* __restrict__ partials, float* __restrict__ out,
                              int npart) {
    __shared__ float sred[4];
    float s = 0.0f;
    for (int t = threadIdx.x; t < npart; t += 256) s += partials[t];
#pragma unroll
    for (int m = 1; m < 64; m <<= 1) s += __shfl_xor(s, m);
    int wave = threadIdx.x >> 6, lane = threadIdx.x & 63;
    if (lane == 0) sred[wave] = s;
    __syncthreads();
    if (threadIdx.x == 0) {
        float tot = (sred[0] + sred[1]) + (sred[2] + sred[3]);
        float loss = tot * (1.0f / 67100672.0f);  // 8192*8191
        out[0] = fmaxf(loss, 0.0f);
    }
}

extern "C" void kernel_launch(void* const* d_in, const int* in_sizes, int n_in,
                              void* d_out, int out_size, void* d_ws, size_t ws_size,
                              hipStream_t stream) {
    const float* p = (const float*)d_in[0];  // [8192,128] f32
    const float* n = (const float*)d_in[1];  // [64,128] f32
    float* out = (float*)d_out;
    char* ws = (char*)d_ws;

    // ws layout
    char*  pb    = ws;                                       // 1 MB (8192 x 128 B fp8)
    float* warr  = (float*)(ws + (1u << 20));                // 32 KB
    float* qarr  = (float*)(ws + (1u << 20) + (32u << 10));  // 32 KB
    float* parts = (float*)(ws + (1u << 20) + (64u << 10));  // NTRI floats

    hipLaunchKernelGGL(rows_kernel, dim3(LP / 4), dim3(256), 0, stream, p, n, pb, warr, qarr);
    hipLaunchKernelGGL(pair_kernel, dim3(NTRI), dim3(512), 0, stream, pb, warr, qarr, parts);
    hipLaunchKernelGGL(reduce_kernel, dim3(1), dim3(256), 0, stream, parts, out, NTRI);
}

// Round 6
// 30.540 us; speedup vs baseline: 1.3779x; 1.3779x over previous
//
#include <hip/hip_runtime.h>
#include <hip/hip_bf16.h>

typedef float f32x16 __attribute__((ext_vector_type(16)));
typedef float f32x4v __attribute__((ext_vector_type(4)));

#define GLOBAL_AS(p) ((const __attribute__((address_space(1))) void*)(p))
#define LDS_AS(p)    ((__attribute__((address_space(3))) void*)(p))

#define LP 8192
#define D 128
#define TWOEPS 2e-6f
#define CEPS 1.28e-10f   /* 128 * EPS^2 */
#define MARGIN 0.2f
#define NTRI 2080        /* 64*65/2 lower-triangular 128x128 tiles */
#define NBLK 512         /* persistent blocks; blk < 32 take a 5th tile */

/* LDS per buffer: A tile 16K | B tile 16K | QW (i-side 1K, j-side 1K) */
#define BUFSZ 34816
#define AOFF 0
#define BOFF 16384
#define QWOFF 32768

// ---------------- Phase A: normalize p rows -> fp8, write qw = (q8, w) ----------------
// pb[row] = fp8_e4m3(p_hat); qw[row] = { ||fp8(p_hat)||^2 , MARGIN - d_pn(row) }
__global__ __launch_bounds__(256) void rows_kernel(const float* __restrict__ p,
                                                   const float* __restrict__ n,
                                                   char* __restrict__ pb,
                                                   float* __restrict__ qw) {
    int tid = threadIdx.x;
    int wave = tid >> 6, lane = tid & 63;
    int row = blockIdx.x * 4 + wave;
    float2 x = ((const float2*)(p + (size_t)row * D))[lane];  // 64 x 2 = 128 = D
    float2 y = ((const float2*)n)[lane];                      // n row 0 (t=0)
    float ssp = fmaf(x.x, x.x, x.y * x.y);
    float ssn = fmaf(y.x, y.x, y.y * y.y);
#pragma unroll
    for (int m = 1; m < 64; m <<= 1) {
        ssp += __shfl_xor(ssp, m);
        ssn += __shfl_xor(ssn, m);
    }
    float invp = 1.0f / fmaxf(sqrtf(ssp), 1e-12f);
    float invn = 1.0f / fmaxf(sqrtf(ssn), 1e-12f);
    float a0 = x.x * invp, a1 = x.y * invp;
    float h0 = y.x * invn, h1 = y.y * invn;

    int pk = __builtin_amdgcn_cvt_pk_fp8_f32(a0, a1, 0, false);
    *(unsigned short*)(pb + (size_t)row * 128 + lane * 2) = (unsigned short)(pk & 0xffff);
    float b0 = __builtin_amdgcn_cvt_f32_fp8(pk, 0);
    float b1 = __builtin_amdgcn_cvt_f32_fp8(pk, 1);

    float q8 = fmaf(b0, b0, b1 * b1);
    float s  = a0 + a1;
    float q  = fmaf(a0, a0, a1 * a1);
    float dn = fmaf(a0, h0, a1 * h1);
    float sn = h0 + h1;
    float qn = fmaf(h0, h0, h1 * h1);
#pragma unroll
    for (int m = 1; m < 64; m <<= 1) {
        q8 += __shfl_xor(q8, m);
        s += __shfl_xor(s, m);
        q += __shfl_xor(q, m);
        dn += __shfl_xor(dn, m);
        sn += __shfl_xor(sn, m);
        qn += __shfl_xor(qn, m);
    }
    if (lane == 0) {
        float sq = q + qn - 2.0f * dn + TWOEPS * (s - sn) + CEPS;
        float dpn = sqrtf(fmaxf(sq, 0.0f));
        *(float2*)(qw + (size_t)row * 2) = make_float2(q8, MARGIN - dpn);
    }
}

// ---------------- Phase B: persistent double-buffered triangular pair kernel ----------
// Block blk processes tiles {blk, blk+512, ...} (4 or 5). Per tile: stage next
// tile (5 global_load_lds / wave, counted vmcnt(5)) while computing current.
// LDS tiles row-major [128 rows][128 B] with XOR chunk-swizzle (chunk ^= row&7):
// global source stays lane-contiguous (1 KB/instr), frag reads 4-way max.
__global__ __launch_bounds__(512, 4) void pair_kernel(const char* __restrict__ pb,
                                                      const float* __restrict__ qw,
                                                      float* __restrict__ partials) {
    __shared__ __align__(16) char smem[2 * BUFSZ];  // 69632 B -> 2 blocks/CU
    const int blk = blockIdx.x;
    const int tid = threadIdx.x;
    const int wave = tid >> 6, lane = tid & 63;
    const int nt = (blk < NTRI - 4 * NBLK) ? 5 : 4;  // 32 blocks take a 5th tile

    const int wr = wave >> 2, wc = wave & 3;  // 2x4 waves, 64x32 output each
    const int ln31 = lane & 31;
    const int h = lane >> 5;

    auto decode = [](int b, int& ti, int& tj) {
        int t = (int)((__builtin_amdgcn_sqrtf(8.0f * (float)b + 1.0f) - 1.0f) * 0.5f);
        while ((t + 1) * (t + 2) / 2 <= b) ++t;
        while (t * (t + 1) / 2 > b) --t;
        ti = t;
        tj = b - t * (t + 1) / 2;
    };

    auto stage = [&](int ti, int tj, char* buf) {
        const char* gA = pb + (size_t)ti * 128 * 128;
        const char* gB = pb + (size_t)tj * 128 * 128;  // diag: same src, both copies
#pragma unroll
        for (int r = 0; r < 2; ++r) {
            int obase = wave * 2048 + r * 1024;  // wave-uniform LDS byte base
            int o = obase + lane * 16;
            int src = o ^ (((o >> 7) & 7) << 4);  // inverse swizzle on global side
            __builtin_amdgcn_global_load_lds(GLOBAL_AS(gA + src),
                                             LDS_AS(buf + AOFF + obase), 16, 0, 0);
            __builtin_amdgcn_global_load_lds(GLOBAL_AS(gB + src),
                                             LDS_AS(buf + BOFF + obase), 16, 0, 0);
        }
        // qw: i-side rows (waves 0-3), j-side rows (waves 4-7); 256 B per wave.
        int side = wave >> 2;
        int chunk = wave & 3;
        const char* gq = (const char*)qw + (size_t)(side ? tj : ti) * 1024 +
                         chunk * 256 + lane * 4;
        __builtin_amdgcn_global_load_lds(GLOBAL_AS(gq),
                                         LDS_AS(buf + QWOFF + side * 1024 + chunk * 256),
                                         4, 0, 0);
    };

    int ti0, tj0;
    decode(blk, ti0, tj0);
    stage(ti0, tj0, smem);  // prologue: tile 0 -> buf 0 (5 loads in flight)
    bool diag_cur = (ti0 == tj0);
    bool diag_nxt = false;

    float la = 0.0f, lb = 0.0f;

    for (int t = 0; t < nt; ++t) {
        char* cur = smem + (size_t)(t & 1) * BUFSZ;
        char* nxt = smem + (size_t)((t + 1) & 1) * BUFSZ;

        if (t + 1 < nt) {
            int ti, tj;
            decode(blk + (t + 1) * NBLK, ti, tj);
            diag_nxt = (ti == tj);
            stage(ti, tj, nxt);  // 5 more loads -> outstanding <= 10
            asm volatile("s_waitcnt vmcnt(5)" ::: "memory");  // cur's 5 done
        } else {
            asm volatile("s_waitcnt vmcnt(0)" ::: "memory");
        }
        __builtin_amdgcn_s_barrier();        // all waves' cur slices landed
        __builtin_amdgcn_sched_barrier(0);

        const char* lA = cur + AOFF;
        const char* lB = cur + BOFF;
        const float* qwi = (const float*)(cur + QWOFF);
        const float* qwj = (const float*)(cur + QWOFF + 1024);

        f32x16 acc[2] = {};
        // A row = wr*64+mt*32+ln31, B col-row = wc*32+ln31; k-chunk ks, half h.
        // Swizzled read: chunk' = ks ^ (row&7); row&7 == ln31&7 for both A and B.
#pragma unroll
        for (int ks = 0; ks < 8; ++ks) {
            int co = ((ks ^ (ln31 & 7)) << 4) + h * 8;
            long bv = *(const long*)(lB + (wc * 32 + ln31) * 128 + co);
#pragma unroll
            for (int mt = 0; mt < 2; ++mt) {
                long av = *(const long*)(lA + (wr * 64 + mt * 32 + ln31) * 128 + co);
                acc[mt] = __builtin_amdgcn_mfma_f32_32x32x16_fp8_fp8(av, bv, acc[mt],
                                                                     0, 0, 0);
            }
        }

        // Epilogue. C/D 32x32: col = ln31, row = (reg&3) + 8*(reg>>2) + 4*h.
        float2 qwjv = *(const float2*)(qwj + (wc * 32 + ln31) * 2);
        if (diag_cur) {
#pragma unroll
            for (int mt = 0; mt < 2; ++mt)
#pragma unroll
                for (int g = 0; g < 4; ++g) {
                    int rbase = wr * 64 + mt * 32 + 8 * g + 4 * h;
                    f32x4v qw01 = *(const f32x4v*)(qwi + rbase * 2);      // rows +0,+1
                    f32x4v qw23 = *(const f32x4v*)(qwi + rbase * 2 + 4);  // rows +2,+3
                    float qi[4] = {qw01[0], qw01[2], qw23[0], qw23[2]};
                    float wi[4] = {qw01[1], qw01[3], qw23[1], qw23[3]};
#pragma unroll
                    for (int r2 = 0; r2 < 4; ++r2) {
                        float sq = fmaf(-2.0f, acc[mt][g * 4 + r2], qi[r2] + qwjv.x);
                        float d = __builtin_amdgcn_sqrtf(fmaxf(sq, 0.0f));
                        la += fmaxf(d + wi[r2], 0.0f);
                    }
                }
        } else {
#pragma unroll
            for (int mt = 0; mt < 2; ++mt)
#pragma unroll
                for (int g = 0; g < 4; ++g) {
                    int rbase = wr * 64 + mt * 32 + 8 * g + 4 * h;
                    f32x4v qw01 = *(const f32x4v*)(qwi + rbase * 2);
                    f32x4v qw23 = *(const f32x4v*)(qwi + rbase * 2 + 4);
                    float qi[4] = {qw01[0], qw01[2], qw23[0], qw23[2]};
                    float wi[4] = {qw01[1], qw01[3], qw23[1], qw23[3]};
#pragma unroll
                    for (int r2 = 0; r2 < 4; ++r2) {
                        float sq = fmaf(-2.0f, acc[mt][g * 4 + r2], qi[r2] + qwjv.x);
                        float d = __builtin_amdgcn_sqrtf(sq);  // off-diag: sq >= ~0.9
                        la += fmaxf(d + wi[r2], 0.0f);   // term (i,j)
                        lb += fmaxf(d + qwjv.y, 0.0f);   // term (j,i)
                    }
                }
        }
        __builtin_amdgcn_s_barrier();  // reads of cur done before it is re-staged
        diag_cur = diag_nxt;
    }

    float local = la + lb;
#pragma unroll
    for (int m = 1; m < 64; m <<= 1) local += __shfl_xor(local, m);
    float* sred = (float*)smem;
    if (lane == 0) sred[wave] = local;
    __syncthreads();
    if (tid == 0) {
        float t0 = (sred[0] + sred[1]) + (sred[2] + sred[3]);
        float t1 = (sred[4] + sred[5]) + (sred[6] + sred[7]);
        partials[blk] = t0 + t1;
    }
}

// ---------------- Phase C: final reduce ----------------
__global__ void reduce_kernel(const float* __restrict__ partials, float* __restrict__ out,
                              int npart) {
    __shared__ float sred[4];
    float s = 0.0f;
    for (int t = threadIdx.x; t < npart; t += 256) s += partials[t];
#pragma unroll
    for (int m = 1; m < 64; m <<= 1) s += __shfl_xor(s, m);
    int wave = threadIdx.x >> 6, lane = threadIdx.x & 63;
    if (lane == 0) sred[wave] = s;
    __syncthreads();
    if (threadIdx.x == 0) {
        float tot = (sred[0] + sred[1]) + (sred[2] + sred[3]);
        float loss = tot * (1.0f / 67100672.0f);  // 8192*8191
        out[0] = fmaxf(loss, 0.0f);
    }
}

extern "C" void kernel_launch(void* const* d_in, const int* in_sizes, int n_in,
                              void* d_out, int out_size, void* d_ws, size_t ws_size,
                              hipStream_t stream) {
    const float* p = (const float*)d_in[0];  // [8192,128] f32
    const float* n = (const float*)d_in[1];  // [64,128] f32
    float* out = (float*)d_out;
    char* ws = (char*)d_ws;

    // ws layout
    char*  pb    = ws;                                       // 1 MB (8192 x 128 B fp8)
    float* qwarr = (float*)(ws + (1u << 20));                // 64 KB (8192 x float2)
    float* parts = (float*)(ws + (1u << 20) + (64u << 10));  // NBLK floats

    hipLaunchKernelGGL(rows_kernel, dim3(LP / 4), dim3(256), 0, stream, p, n, pb, qwarr);
    hipLaunchKernelGGL(pair_kernel, dim3(NBLK), dim3(512), 0, stream, pb, qwarr, parts);
    hipLaunchKernelGGL(reduce_kernel, dim3(1), dim3(256), 0, stream, parts, out, NBLK);
}